// Round 9
// baseline (138.522 us; speedup 1.0000x reference)
//
#include <hip/hip_runtime.h>

// Problem constants from setup_inputs(): shape (64, 16, 64, 64), fp32, kern=2.
#define N_ 64
#define C_ 16
#define H_ 64
#define W_ 64

// pair tiling: R12 structure EXACTLY (best measured, total 136.2us): 4 i-rows
// x 8 j-rows per tile, D in 16 chunks of 1024, natural block order.
// tri sets (vaa, vbb): i-tile g needs j-tiles 0..(g>>1) -> 72 tiles/set.
// vab (full): 16 x 8 = 128 tiles. TILES = 72*2 + 128 = 272.
#define TRI_TILES 72
#define TILES 272
#define DCHUNKS 16
#define PAIR_BLOCKS (TILES * DCHUNKS)   // 4352

// NUMERICS: ws stores var' = var * 2ln2. exp(-0.5 d^2/v)/sqrt(v)
//   = exp2(-(d*rsq(v'))^2) * rsq(v') * sqrt(2ln2). 2 transc + 2.5 pk-VALU/term.
#define TWO_LN2   1.3862943611198906f
#define SQRT_2LN2 1.1774100225154747f

// ws layout (floats): [0..Np) mu_a | [Np..2Np) var'_a | [2Np..3Np) mu_b |
// [3Np..4Np) var'_b | [4Np..4Np+PAIR_BLOCKS) per-block partials.
// Post-mortem ledger:
// R8:  reg prefetch -> VGPR 96, occ down, +4%. Register spend loses waves.
// R9:  XCD pinning -> +21%. Natural order's locality wins.
// R10: 512-thr blocks -> +23%. Footprint dilution.
// R11: 8x8 reg tile, VGPR 140 -> slower. Per-thread state costs waves.
// R12: packed f32 + collapsed accs -> pair 45.6 -> ~37us. BEST (136.2 total).
// R13: depth-1 LDS j-staging -> neutral (lookahead < latency).
// R14: LDS i-tile one-shot stage -> 47us; resident blocks' stage phases
//      collide. KEY: VALU busy ~27us in all variants = issue floor.
// R15: 4x16 tile (blocks/2, traffic/2.3) -> neutral. Per-block overhead is
//      NOT the residual; stall is per-iteration load latency at 2 waves/SIMD
//      (2x320cy compute / (500+320) = 78% ~= measured VALUBusy).
// R16 (this): cross the 64-VGPR residency boundary (waves/SIMD steps at
//      64/128/256). Split pair into pair_fast (k==2 only, launch_bounds
//      (256,8) => VGPR<=64) + pair_generic (k!=2, unconstrained). Both
//      launch; device-side guard no-ops one. Tiling/inner loop = R12 exact.

typedef __attribute__((ext_vector_type(2))) float f32x2;

__global__ __launch_bounds__(256) void pool_kernel(
    const float* __restrict__ mu_a, const float* __restrict__ lv_a,
    const float* __restrict__ mu_b, const float* __restrict__ lv_b,
    const int* __restrict__ kern_p, float* __restrict__ ws) {
    const int k = kern_p[0];
    const float LOG2E = 1.44269504088896f;

    if (k == 2) {
        // Fast path: 4 contiguous pooled outputs per thread, all-shift indexing.
        const int Np = (N_ * C_ * H_ * W_) >> 2;  // 1048576
        const int Q  = Np >> 2;                   // 262144 quads per array
        const int total = 4 * Q;
        for (int g = blockIdx.x * blockDim.x + threadIdx.x; g < total;
             g += gridDim.x * blockDim.x) {
            const int a  = g >> 18;               // log2(Q) = 18
            const int r4 = g & (Q - 1);
            const int pw4 = (r4 & 7) << 2;        // Wp=32 -> 8 quads/row
            const int t   = r4 >> 3;
            const int ph  = t & 31;               // Hp=32
            const int nc  = t >> 5;
            const float* src = (a == 0) ? mu_a : (a == 1) ? lv_a : (a == 2) ? mu_b : lv_b;
            const bool is_var = (a & 1);
            const float* p0 = src + nc * (H_ * W_) + (ph * 2) * W_ + pw4 * 2;
            float4 r0a = *(const float4*)(p0);
            float4 r0b = *(const float4*)(p0 + 4);
            float4 r1a = *(const float4*)(p0 + W_);
            float4 r1b = *(const float4*)(p0 + W_ + 4);
            float o0, o1, o2, o3;
            if (is_var) {
#define E_(x) __builtin_amdgcn_exp2f((x) * LOG2E)
                o0 = E_(r0a.x) + E_(r0a.y) + E_(r1a.x) + E_(r1a.y);
                o1 = E_(r0a.z) + E_(r0a.w) + E_(r1a.z) + E_(r1a.w);
                o2 = E_(r0b.x) + E_(r0b.y) + E_(r1b.x) + E_(r1b.y);
                o3 = E_(r0b.z) + E_(r0b.w) + E_(r1b.z) + E_(r1b.w);
#undef E_
                const float s = (1.0f / 16.0f) * TWO_LN2;  // 1/k^4 * 2ln2
                o0 *= s; o1 *= s; o2 *= s; o3 *= s;
            } else {
                o0 = r0a.x + r0a.y + r1a.x + r1a.y;
                o1 = r0a.z + r0a.w + r1a.z + r1a.w;
                o2 = r0b.x + r0b.y + r1b.x + r1b.y;
                o3 = r0b.z + r0b.w + r1b.z + r1b.w;
                const float s = 0.25f;            // 1/k^2
                o0 *= s; o1 *= s; o2 *= s; o3 *= s;
            }
            *(float4*)(ws + (size_t)a * Np + (size_t)r4 * 4) = make_float4(o0, o1, o2, o3);
        }
    } else {
        // Generic fallback (any k dividing 64).
        const int Hp = H_ / k, Wp = W_ / k;
        const int Np = N_ * C_ * Hp * Wp;
        const float inv_k2 = 1.0f / (float)(k * k);
        const float inv_k4 = inv_k2 * inv_k2 * TWO_LN2;   // fold var pre-scale
        const int total = 4 * Np;
        for (int p = blockIdx.x * blockDim.x + threadIdx.x; p < total;
             p += gridDim.x * blockDim.x) {
            const int a  = p / Np;
            const int r  = p - a * Np;
            const int pw = r % Wp;
            const int t1 = r / Wp;
            const int ph = t1 % Hp;
            const int nc = t1 / Hp;
            const float* src = (a == 0) ? mu_a : (a == 1) ? lv_a : (a == 2) ? mu_b : lv_b;
            const bool is_var = (a & 1);
            const int base = nc * (H_ * W_) + (ph * k) * W_ + (pw * k);
            float s = 0.0f;
            for (int dy = 0; dy < k; ++dy) {
                const float* row = src + base + dy * W_;
                for (int dx = 0; dx < k; ++dx) {
                    float x = row[dx];
                    s += is_var ? __builtin_amdgcn_exp2f(x * LOG2E) : x;
                }
            }
            ws[(size_t)a * Np + r] = s * (is_var ? inv_k4 : inv_k2);
        }
    }
}

// Packed 2-term Gaussian chain: v_pk_add / v_pk_mul / v_pk_fma on f32x2,
// scalar rsq/exp2 per component (no packed transcendentals exist).
#define TERM2(ACC, IM, IV, JM, JV)                                     \
    {                                                                  \
        f32x2 v_  = (IV) + (JV);                                       \
        f32x2 rs_; rs_.x = __builtin_amdgcn_rsqf(v_.x);                \
                   rs_.y = __builtin_amdgcn_rsqf(v_.y);                \
        f32x2 d_  = (IM) - (JM);                                       \
        f32x2 t_  = d_ * rs_;                                          \
        f32x2 nt_ = -t_ * t_;                                          \
        f32x2 e_; e_.x = __builtin_amdgcn_exp2f(nt_.x);                \
                  e_.y = __builtin_amdgcn_exp2f(nt_.y);                \
        ACC += e_ * rs_;                                               \
    }

// k==2 only. launch_bounds(256, 8): 8 waves/EU min => VGPR cap 64 (the
// residency-step boundary). Live state: 32 i-regs + 8 acc + 8 j transient +
// ~12 addr/misc ~= 60. If the allocator spills, that is this round's
// falsifier (c) — revert the bound.
__global__ __launch_bounds__(256, 8) void pair_fast(float* __restrict__ ws,
                                                    const int* __restrict__ kern_p) {
    if (kern_p[0] != 2) return;
    const int Np = 1048576;                  // 64 * 16384
    const float* mu_a = ws;
    const float* va   = ws + (size_t)Np;
    const float* mu_b = ws + (size_t)2 * Np;
    const float* vb   = ws + (size_t)3 * Np;
    float* partials   = ws + (size_t)4 * Np;

    // ---- decode block -> (tile, chunk), R12 natural order ----
    const int c = blockIdx.x & (DCHUNKS - 1);
    const int t = blockIdx.x >> 4;           // DCHUNKS == 16
    int set, it, jt;
    if (t >= 2 * TRI_TILES) {
        set = 2;
        const int tt = t - 2 * TRI_TILES;
        it = tt >> 3;
        jt = tt & 7;
    } else {
        set = (t >= TRI_TILES) ? 1 : 0;
        const int tt = set ? (t - TRI_TILES) : t;
        int g = 0, cum = 0;
        while (cum + (g >> 1) + 1 <= tt) { cum += (g >> 1) + 1; ++g; }
        it = g;
        jt = tt - cum;
    }
    const int i0 = it * 4, j0 = jt * 8;

    const float *mu1, *v1, *mu2, *v2;
    if (set == 0)      { mu1 = mu2 = mu_a; v1 = v2 = va; }
    else if (set == 1) { mu1 = mu2 = mu_b; v1 = v2 = vb; }
    else               { mu1 = mu_a; v1 = va; mu2 = mu_b; v2 = vb; }

    // Uniform tiles: set 2 (w=-2) and tri tiles strictly below the diagonal
    // (jt < it>>1). Mixed (diagonal band): jt == it>>1, 32 of 272 tiles.
    const bool uniform = (set == 2) || (jt < (it >> 1));
    const float wU = (set == 2) ? -2.0f : 2.0f;

    float tot = 0.0f;
    const int base = (c << 10) + ((int)threadIdx.x << 2);

    // i-state: 4 rows x {mu,v'} x {lo,hi} f32x2 = 32 VGPR.
    f32x2 imlo[4], imhi[4], ivlo[4], ivhi[4];
    #pragma unroll
    for (int ir = 0; ir < 4; ++ir) {
        const float4 m4 = *(const float4*)(mu1 + (size_t)(i0 + ir) * 16384 + base);
        const float4 v4 = *(const float4*)(v1  + (size_t)(i0 + ir) * 16384 + base);
        imlo[ir].x = m4.x; imlo[ir].y = m4.y; imhi[ir].x = m4.z; imhi[ir].y = m4.w;
        ivlo[ir].x = v4.x; ivlo[ir].y = v4.y; ivhi[ir].x = v4.z; ivhi[ir].y = v4.w;
    }
    const float* gjm = mu2 + (size_t)j0 * 16384 + base;
    const float* gjv = v2  + (size_t)j0 * 16384 + base;

    if (uniform) {
        // One packed accumulator per i-row (8 regs); weight applied once.
        f32x2 acc2[4];
        #pragma unroll
        for (int ir = 0; ir < 4; ++ir) { acc2[ir].x = 0.0f; acc2[ir].y = 0.0f; }
        #pragma unroll
        for (int j8 = 0; j8 < 8; ++j8) {
            const float4 jm = *(const float4*)(gjm + (size_t)j8 * 16384);
            const float4 jv = *(const float4*)(gjv + (size_t)j8 * 16384);
            f32x2 jmlo, jmhi, jvlo, jvhi;
            jmlo.x = jm.x; jmlo.y = jm.y; jmhi.x = jm.z; jmhi.y = jm.w;
            jvlo.x = jv.x; jvlo.y = jv.y; jvhi.x = jv.z; jvhi.y = jv.w;
            #pragma unroll
            for (int ir = 0; ir < 4; ++ir) {
                TERM2(acc2[ir], imlo[ir], ivlo[ir], jmlo, jvlo)
                TERM2(acc2[ir], imhi[ir], ivhi[ir], jmhi, jvhi)
            }
        }
        const f32x2 s2 = (acc2[0] + acc2[1]) + (acc2[2] + acc2[3]);
        tot = wU * (s2.x + s2.y);
    } else {
        // Mixed tile (tri diagonal band): fold 0/1/2 weight per (ir,j8).
        #pragma unroll
        for (int j8 = 0; j8 < 8; ++j8) {
            const float4 jm = *(const float4*)(gjm + (size_t)j8 * 16384);
            const float4 jv = *(const float4*)(gjv + (size_t)j8 * 16384);
            f32x2 jmlo, jmhi, jvlo, jvhi;
            jmlo.x = jm.x; jmlo.y = jm.y; jmhi.x = jm.z; jmhi.y = jm.w;
            jvlo.x = jv.x; jvlo.y = jv.y; jvhi.x = jv.z; jvhi.y = jv.w;
            const int jj = j0 + j8;
            #pragma unroll
            for (int ir = 0; ir < 4; ++ir) {
                f32x2 a; a.x = 0.0f; a.y = 0.0f;
                TERM2(a, imlo[ir], ivlo[ir], jmlo, jvlo)
                TERM2(a, imhi[ir], ivhi[ir], jmhi, jvhi)
                const int ii = i0 + ir;
                const float w = (jj > ii) ? 0.0f : (jj == ii) ? 1.0f : 2.0f;
                tot = fmaf(w, a.x + a.y, tot);
            }
        }
    }

    tot *= SQRT_2LN2;   // fold the var'-prescale correction once

    for (int off = 32; off > 0; off >>= 1)
        tot += __shfl_down(tot, off, 64);
    __shared__ float wsum[4];
    const int lane = threadIdx.x & 63;
    const int wid  = threadIdx.x >> 6;
    if (lane == 0) wsum[wid] = tot;
    __syncthreads();
    if (threadIdx.x == 0) {
        partials[blockIdx.x] = wsum[0] + wsum[1] + wsum[2] + wsum[3];
    }
}

// Any k != 2 (k divides 64): scalar loads, runtime weights. Unconstrained.
__global__ __launch_bounds__(256) void pair_generic(float* __restrict__ ws,
                                                    const int* __restrict__ kern_p) {
    const int k = kern_p[0];
    if (k == 2) return;
    const int D  = C_ * (H_ / k) * (W_ / k);
    const int Np = N_ * D;
    const float* mu_a = ws;
    const float* va   = ws + (size_t)Np;
    const float* mu_b = ws + (size_t)2 * Np;
    const float* vb   = ws + (size_t)3 * Np;
    float* partials   = ws + (size_t)4 * Np;

    const int c = blockIdx.x & (DCHUNKS - 1);
    const int t = blockIdx.x >> 4;
    int set, it, jt;
    if (t >= 2 * TRI_TILES) {
        set = 2;
        const int tt = t - 2 * TRI_TILES;
        it = tt >> 3;
        jt = tt & 7;
    } else {
        set = (t >= TRI_TILES) ? 1 : 0;
        const int tt = set ? (t - TRI_TILES) : t;
        int g = 0, cum = 0;
        while (cum + (g >> 1) + 1 <= tt) { cum += (g >> 1) + 1; ++g; }
        it = g;
        jt = tt - cum;
    }
    const int i0 = it * 4, j0 = jt * 8;

    const float *mu1, *v1, *mu2, *v2;
    if (set == 0)      { mu1 = mu2 = mu_a; v1 = v2 = va; }
    else if (set == 1) { mu1 = mu2 = mu_b; v1 = v2 = vb; }
    else               { mu1 = mu_a; v1 = va; mu2 = mu_b; v2 = vb; }

    float tot = 0.0f;
    const int cs = D / DCHUNKS;
    const int lo = c * cs, hi = lo + cs;
    for (int e = lo + (int)threadIdx.x; e < hi; e += 256) {
        #pragma unroll
        for (int j8 = 0; j8 < 8; ++j8) {
            const int jj = j0 + j8;
            const float mj = mu2[(size_t)jj * D + e];
            const float vj = v2 [(size_t)jj * D + e];
            #pragma unroll
            for (int ir = 0; ir < 4; ++ir) {
                const int ii = i0 + ir;
                const float w = (set == 2) ? -2.0f
                              : (jj > ii) ? 0.0f : (jj == ii) ? 1.0f : 2.0f;
                const float mi = mu1[(size_t)ii * D + e];
                const float vi = v1 [(size_t)ii * D + e];
                float v_  = vi + vj;
                float rs_ = __builtin_amdgcn_rsqf(v_);
                float d_  = mi - mj;
                float t_  = d_ * rs_;
                float e_  = __builtin_amdgcn_exp2f(-(t_ * t_));
                tot = fmaf(w, e_ * rs_, tot);
            }
        }
    }

    tot *= SQRT_2LN2;

    for (int off = 32; off > 0; off >>= 1)
        tot += __shfl_down(tot, off, 64);
    __shared__ float wsum[4];
    const int lane = threadIdx.x & 63;
    const int wid  = threadIdx.x >> 6;
    if (lane == 0) wsum[wid] = tot;
    __syncthreads();
    if (threadIdx.x == 0) {
        partials[blockIdx.x] = wsum[0] + wsum[1] + wsum[2] + wsum[3];
    }
}

// Single block: sum the PAIR_BLOCKS partials into out[0].
__global__ __launch_bounds__(256) void reduce_kernel(const float* __restrict__ ws,
                                                     const int* __restrict__ kern_p,
                                                     float* __restrict__ out) {
    const int k = kern_p[0];
    const int D  = C_ * (H_ / k) * (W_ / k);
    const int Np = N_ * D;
    const float* partials = ws + (size_t)4 * Np;

    float s = 0.0f;
    for (int p = threadIdx.x; p < PAIR_BLOCKS; p += 256) s += partials[p];
    for (int off = 32; off > 0; off >>= 1)
        s += __shfl_down(s, off, 64);
    __shared__ float wsum[4];
    const int lane = threadIdx.x & 63;
    const int wid  = threadIdx.x >> 6;
    if (lane == 0) wsum[wid] = s;
    __syncthreads();
    if (threadIdx.x == 0) out[0] = wsum[0] + wsum[1] + wsum[2] + wsum[3];
}

extern "C" void kernel_launch(void* const* d_in, const int* in_sizes, int n_in,
                              void* d_out, int out_size, void* d_ws, size_t ws_size,
                              hipStream_t stream) {
    const float* mu_a = (const float*)d_in[0];
    const float* lv_a = (const float*)d_in[1];
    const float* mu_b = (const float*)d_in[2];
    const float* lv_b = (const float*)d_in[3];
    const int*   kern = (const int*)d_in[4];
    float* out = (float*)d_out;
    float* ws  = (float*)d_ws;

    pool_kernel<<<4096, 256, 0, stream>>>(mu_a, lv_a, mu_b, lv_b, kern, ws);
    pair_fast<<<PAIR_BLOCKS, 256, 0, stream>>>(ws, kern);
    pair_generic<<<PAIR_BLOCKS, 256, 0, stream>>>(ws, kern);
    reduce_kernel<<<1, 256, 0, stream>>>(ws, kern, out);
}

// Round 10
// 137.645 us; speedup vs baseline: 1.0064x; 1.0064x over previous
//
#include <hip/hip_runtime.h>

// Problem constants from setup_inputs(): shape (64, 16, 64, 64), fp32, kern=2.
#define N_ 64
#define C_ 16
#define H_ 64
#define W_ 64

// pair_kernel tiling: R5/R12 structure (best measured, total 136.15us):
// 4 i-rows x 8 j-rows per tile, D in 16 chunks of 1024, natural block order.
// tri sets (vaa, vbb): i-tile g needs j-tiles 0..(g>>1) -> 72 tiles/set.
// vab (full): 16 x 8 = 128 tiles. TILES = 72*2 + 128 = 272.
#define TRI_TILES 72
#define TILES 272
#define DCHUNKS 16
#define PAIR_BLOCKS (TILES * DCHUNKS)   // 4352

// NUMERICS: ws stores var' = var * 2ln2. exp(-0.5 d^2/v)/sqrt(v)
//   = exp2(-(d*rsq(v'))^2) * rsq(v') * sqrt(2ln2). 2 transc + 2.5 pk-VALU/term.
#define TWO_LN2   1.3862943611198906f
#define SQRT_2LN2 1.1774100225154747f

// ws layout (floats): [0..Np) mu_a | [Np..2Np) var'_a | [2Np..3Np) mu_b |
// [3Np..4Np) var'_b | [4Np..4Np+PAIR_BLOCKS) per-block partials.
//
// FINAL ledger (why this shape is the floor):
// R7:  atomicAdd tail serialized -> partials + 1-block reduce.
// R8:  reg prefetch -> VGPR 96, occ down, +4%. Compiler already pipelines to
//      its register budget; manual depth costs waves.
// R9:  XCD pinning -> +21%. Natural order's locality wins.
// R10: 512-thr blocks -> +23%. Footprint dilution.
// R11: 8x8 reg tile (traffic /1.5) -> slower. LATENCY-bound, not BW-bound.
// R12: packed f32 (v_pk_*) + collapsed accs -> pair 45.6 -> ~37us. WIN.
// R13: depth-1 LDS j-staging -> neutral (lookahead < load latency).
// R14: LDS i-tile one-shot stage -> 47us (stage phases collide).
//      KEY: VALU busy ~27us in ALL variants = issue floor (transc ~18us).
// R15: 4x16 tile (blocks/2, traffic/2.3) -> neutral. Per-block overhead not
//      the residual.
// R16: VGPR<=64 via launch_bounds(256,8) -> neutral. Occupancy axis exhausted;
//      the ~10us above busy-floor is irreducible per-iteration load latency.
// Total is dominated by ~99us fixed harness cost (256MB ws poison fill 43us,
// pool ~15us at ~5.3TB/s ~ HBM roofline, launches). pair ~37us vs 27us busy
// floor; all six distinct levers for the gap are neutral-or-worse. FLOOR.

typedef __attribute__((ext_vector_type(2))) float f32x2;

__global__ __launch_bounds__(256) void pool_kernel(
    const float* __restrict__ mu_a, const float* __restrict__ lv_a,
    const float* __restrict__ mu_b, const float* __restrict__ lv_b,
    const int* __restrict__ kern_p, float* __restrict__ ws) {
    const int k = kern_p[0];
    const float LOG2E = 1.44269504088896f;

    if (k == 2) {
        // Fast path: 4 contiguous pooled outputs per thread, all-shift indexing.
        const int Np = (N_ * C_ * H_ * W_) >> 2;  // 1048576
        const int Q  = Np >> 2;                   // 262144 quads per array
        const int total = 4 * Q;
        for (int g = blockIdx.x * blockDim.x + threadIdx.x; g < total;
             g += gridDim.x * blockDim.x) {
            const int a  = g >> 18;               // log2(Q) = 18
            const int r4 = g & (Q - 1);
            const int pw4 = (r4 & 7) << 2;        // Wp=32 -> 8 quads/row
            const int t   = r4 >> 3;
            const int ph  = t & 31;               // Hp=32
            const int nc  = t >> 5;
            const float* src = (a == 0) ? mu_a : (a == 1) ? lv_a : (a == 2) ? mu_b : lv_b;
            const bool is_var = (a & 1);
            const float* p0 = src + nc * (H_ * W_) + (ph * 2) * W_ + pw4 * 2;
            float4 r0a = *(const float4*)(p0);
            float4 r0b = *(const float4*)(p0 + 4);
            float4 r1a = *(const float4*)(p0 + W_);
            float4 r1b = *(const float4*)(p0 + W_ + 4);
            float o0, o1, o2, o3;
            if (is_var) {
#define E_(x) __builtin_amdgcn_exp2f((x) * LOG2E)
                o0 = E_(r0a.x) + E_(r0a.y) + E_(r1a.x) + E_(r1a.y);
                o1 = E_(r0a.z) + E_(r0a.w) + E_(r1a.z) + E_(r1a.w);
                o2 = E_(r0b.x) + E_(r0b.y) + E_(r1b.x) + E_(r1b.y);
                o3 = E_(r0b.z) + E_(r0b.w) + E_(r1b.z) + E_(r1b.w);
#undef E_
                const float s = (1.0f / 16.0f) * TWO_LN2;  // 1/k^4 * 2ln2
                o0 *= s; o1 *= s; o2 *= s; o3 *= s;
            } else {
                o0 = r0a.x + r0a.y + r1a.x + r1a.y;
                o1 = r0a.z + r0a.w + r1a.z + r1a.w;
                o2 = r0b.x + r0b.y + r1b.x + r1b.y;
                o3 = r0b.z + r0b.w + r1b.z + r1b.w;
                const float s = 0.25f;            // 1/k^2
                o0 *= s; o1 *= s; o2 *= s; o3 *= s;
            }
            *(float4*)(ws + (size_t)a * Np + (size_t)r4 * 4) = make_float4(o0, o1, o2, o3);
        }
    } else {
        // Generic fallback (any k dividing 64).
        const int Hp = H_ / k, Wp = W_ / k;
        const int Np = N_ * C_ * Hp * Wp;
        const float inv_k2 = 1.0f / (float)(k * k);
        const float inv_k4 = inv_k2 * inv_k2 * TWO_LN2;   // fold var pre-scale
        const int total = 4 * Np;
        for (int p = blockIdx.x * blockDim.x + threadIdx.x; p < total;
             p += gridDim.x * blockDim.x) {
            const int a  = p / Np;
            const int r  = p - a * Np;
            const int pw = r % Wp;
            const int t1 = r / Wp;
            const int ph = t1 % Hp;
            const int nc = t1 / Hp;
            const float* src = (a == 0) ? mu_a : (a == 1) ? lv_a : (a == 2) ? mu_b : lv_b;
            const bool is_var = (a & 1);
            const int base = nc * (H_ * W_) + (ph * k) * W_ + (pw * k);
            float s = 0.0f;
            for (int dy = 0; dy < k; ++dy) {
                const float* row = src + base + dy * W_;
                for (int dx = 0; dx < k; ++dx) {
                    float x = row[dx];
                    s += is_var ? __builtin_amdgcn_exp2f(x * LOG2E) : x;
                }
            }
            ws[(size_t)a * Np + r] = s * (is_var ? inv_k4 : inv_k2);
        }
    }
}

// Packed 2-term Gaussian chain: v_pk_add / v_pk_mul / v_pk_fma on f32x2,
// scalar rsq/exp2 per component (no packed transcendentals exist).
#define TERM2(ACC, IM, IV, JM, JV)                                     \
    {                                                                  \
        f32x2 v_  = (IV) + (JV);                                       \
        f32x2 rs_; rs_.x = __builtin_amdgcn_rsqf(v_.x);                \
                   rs_.y = __builtin_amdgcn_rsqf(v_.y);                \
        f32x2 d_  = (IM) - (JM);                                       \
        f32x2 t_  = d_ * rs_;                                          \
        f32x2 nt_ = -t_ * t_;                                          \
        f32x2 e_; e_.x = __builtin_amdgcn_exp2f(nt_.x);                \
                  e_.y = __builtin_amdgcn_exp2f(nt_.y);                \
        ACC += e_ * rs_;                                               \
    }

__global__ __launch_bounds__(256) void pair_kernel(float* __restrict__ ws,
                                                   const int* __restrict__ kern_p) {
    const int k = kern_p[0];
    const int D  = C_ * (H_ / k) * (W_ / k);
    const int Np = N_ * D;

    const float* mu_a = ws;
    const float* va   = ws + (size_t)Np;
    const float* mu_b = ws + (size_t)2 * Np;
    const float* vb   = ws + (size_t)3 * Np;
    float* partials   = ws + (size_t)4 * Np;

    // ---- decode block -> (tile, chunk), natural order ----
    const int c = blockIdx.x & (DCHUNKS - 1);
    const int t = blockIdx.x >> 4;           // DCHUNKS == 16
    int set, it, jt;
    if (t >= 2 * TRI_TILES) {
        set = 2;
        const int tt = t - 2 * TRI_TILES;
        it = tt >> 3;
        jt = tt & 7;
    } else {
        set = (t >= TRI_TILES) ? 1 : 0;
        const int tt = set ? (t - TRI_TILES) : t;
        int g = 0, cum = 0;
        while (cum + (g >> 1) + 1 <= tt) { cum += (g >> 1) + 1; ++g; }
        it = g;
        jt = tt - cum;
    }
    const int i0 = it * 4, j0 = jt * 8;

    const float *mu1, *v1, *mu2, *v2;
    if (set == 0)      { mu1 = mu2 = mu_a; v1 = v2 = va; }
    else if (set == 1) { mu1 = mu2 = mu_b; v1 = v2 = vb; }
    else               { mu1 = mu_a; v1 = va; mu2 = mu_b; v2 = vb; }

    // Uniform tiles: set 2 (w=-2) and tri tiles strictly below the diagonal
    // (jt < it>>1, w=2). Mixed (diagonal band): jt == it>>1, 32 of 272 tiles.
    const bool uniform = (set == 2) || (jt < (it >> 1));
    const float wU = (set == 2) ? -2.0f : 2.0f;

    float tot = 0.0f;

    if (D == 16384) {
        // Fast path: chunk = 1024 elems = 256 threads x 1 float4.
        const int base = (c << 10) + ((int)threadIdx.x << 2);
        // i-state: 4 rows x {mu,v'} x {lo,hi} f32x2 = 32 VGPR.
        f32x2 imlo[4], imhi[4], ivlo[4], ivhi[4];
        #pragma unroll
        for (int ir = 0; ir < 4; ++ir) {
            const float4 m4 = *(const float4*)(mu1 + (size_t)(i0 + ir) * 16384 + base);
            const float4 v4 = *(const float4*)(v1  + (size_t)(i0 + ir) * 16384 + base);
            imlo[ir].x = m4.x; imlo[ir].y = m4.y; imhi[ir].x = m4.z; imhi[ir].y = m4.w;
            ivlo[ir].x = v4.x; ivlo[ir].y = v4.y; ivhi[ir].x = v4.z; ivhi[ir].y = v4.w;
        }
        const float* gjm = mu2 + (size_t)j0 * 16384 + base;
        const float* gjv = v2  + (size_t)j0 * 16384 + base;

        if (uniform) {
            // One packed accumulator per i-row (8 regs); weight applied once.
            f32x2 acc2[4];
            #pragma unroll
            for (int ir = 0; ir < 4; ++ir) { acc2[ir].x = 0.0f; acc2[ir].y = 0.0f; }
            #pragma unroll
            for (int j8 = 0; j8 < 8; ++j8) {
                const float4 jm = *(const float4*)(gjm + (size_t)j8 * 16384);
                const float4 jv = *(const float4*)(gjv + (size_t)j8 * 16384);
                f32x2 jmlo, jmhi, jvlo, jvhi;
                jmlo.x = jm.x; jmlo.y = jm.y; jmhi.x = jm.z; jmhi.y = jm.w;
                jvlo.x = jv.x; jvlo.y = jv.y; jvhi.x = jv.z; jvhi.y = jv.w;
                #pragma unroll
                for (int ir = 0; ir < 4; ++ir) {
                    TERM2(acc2[ir], imlo[ir], ivlo[ir], jmlo, jvlo)
                    TERM2(acc2[ir], imhi[ir], ivhi[ir], jmhi, jvhi)
                }
            }
            const f32x2 s2 = (acc2[0] + acc2[1]) + (acc2[2] + acc2[3]);
            tot = wU * (s2.x + s2.y);
        } else {
            // Mixed tile (tri diagonal band): fold 0/1/2 weight per (ir,j8).
            #pragma unroll
            for (int j8 = 0; j8 < 8; ++j8) {
                const float4 jm = *(const float4*)(gjm + (size_t)j8 * 16384);
                const float4 jv = *(const float4*)(gjv + (size_t)j8 * 16384);
                f32x2 jmlo, jmhi, jvlo, jvhi;
                jmlo.x = jm.x; jmlo.y = jm.y; jmhi.x = jm.z; jmhi.y = jm.w;
                jvlo.x = jv.x; jvlo.y = jv.y; jvhi.x = jv.z; jvhi.y = jv.w;
                const int jj = j0 + j8;
                #pragma unroll
                for (int ir = 0; ir < 4; ++ir) {
                    f32x2 a; a.x = 0.0f; a.y = 0.0f;
                    TERM2(a, imlo[ir], ivlo[ir], jmlo, jvlo)
                    TERM2(a, imhi[ir], ivhi[ir], jmhi, jvhi)
                    const int ii = i0 + ir;
                    const float w = (jj > ii) ? 0.0f : (jj == ii) ? 1.0f : 2.0f;
                    tot = fmaf(w, a.x + a.y, tot);
                }
            }
        }
    } else {
        // Generic fallback: scalar, weight folded per (ir,j8), single scalar
        // accumulator (keeps fallback register pressure from inflating the
        // kernel's VGPR allocation).
        const int cs = D / DCHUNKS;
        const int lo = c * cs, hi = lo + cs;
        for (int e = lo + (int)threadIdx.x; e < hi; e += 256) {
            #pragma unroll
            for (int j8 = 0; j8 < 8; ++j8) {
                const int jj = j0 + j8;
                const float mj = mu2[(size_t)jj * D + e];
                const float vj = v2 [(size_t)jj * D + e];
                #pragma unroll
                for (int ir = 0; ir < 4; ++ir) {
                    const int ii = i0 + ir;
                    const float w = (set == 2) ? -2.0f
                                  : (jj > ii) ? 0.0f : (jj == ii) ? 1.0f : 2.0f;
                    const float mi = mu1[(size_t)ii * D + e];
                    const float vi = v1 [(size_t)ii * D + e];
                    float v_  = vi + vj;
                    float rs_ = __builtin_amdgcn_rsqf(v_);
                    float d_  = mi - mj;
                    float t_  = d_ * rs_;
                    float e_  = __builtin_amdgcn_exp2f(-(t_ * t_));
                    tot = fmaf(w, e_ * rs_, tot);
                }
            }
        }
    }

    tot *= SQRT_2LN2;   // fold the var'-prescale correction once

    for (int off = 32; off > 0; off >>= 1)
        tot += __shfl_down(tot, off, 64);
    __shared__ float wsum[4];
    const int lane = threadIdx.x & 63;
    const int wid  = threadIdx.x >> 6;
    if (lane == 0) wsum[wid] = tot;
    __syncthreads();
    if (threadIdx.x == 0) {
        partials[blockIdx.x] = wsum[0] + wsum[1] + wsum[2] + wsum[3];
    }
}

// Single block: sum the PAIR_BLOCKS partials into out[0].
__global__ __launch_bounds__(256) void reduce_kernel(const float* __restrict__ ws,
                                                     const int* __restrict__ kern_p,
                                                     float* __restrict__ out) {
    const int k = kern_p[0];
    const int D  = C_ * (H_ / k) * (W_ / k);
    const int Np = N_ * D;
    const float* partials = ws + (size_t)4 * Np;

    float s = 0.0f;
    for (int p = threadIdx.x; p < PAIR_BLOCKS; p += 256) s += partials[p];
    for (int off = 32; off > 0; off >>= 1)
        s += __shfl_down(s, off, 64);
    __shared__ float wsum[4];
    const int lane = threadIdx.x & 63;
    const int wid  = threadIdx.x >> 6;
    if (lane == 0) wsum[wid] = s;
    __syncthreads();
    if (threadIdx.x == 0) out[0] = wsum[0] + wsum[1] + wsum[2] + wsum[3];
}

extern "C" void kernel_launch(void* const* d_in, const int* in_sizes, int n_in,
                              void* d_out, int out_size, void* d_ws, size_t ws_size,
                              hipStream_t stream) {
    const float* mu_a = (const float*)d_in[0];
    const float* lv_a = (const float*)d_in[1];
    const float* mu_b = (const float*)d_in[2];
    const float* lv_b = (const float*)d_in[3];
    const int*   kern = (const int*)d_in[4];
    float* out = (float*)d_out;
    float* ws  = (float*)d_ws;

    pool_kernel<<<4096, 256, 0, stream>>>(mu_a, lv_a, mu_b, lv_b, kern, ws);
    pair_kernel<<<PAIR_BLOCKS, 256, 0, stream>>>(ws, kern);
    reduce_kernel<<<1, 256, 0, stream>>>(ws, kern, out);
}